// Round 5
// baseline (713.914 us; speedup 1.0000x reference)
//
#include <hip/hip_runtime.h>
#include <hip/hip_bf16.h>

// AttributeGNN, bf16 MFMA, fp32 accumulate. B=16384, A=16, D=256.
// R5: 3-pass batch-streaming. Each pass has a tiny L2-resident weight set
// (256KB / 2MB / 2MB - no rotation), 32KB LDS, 4 blocks/CU x 4 waves.

typedef __bf16 bf16_t;
typedef __bf16 bf16x4 __attribute__((ext_vector_type(4)));
typedef __bf16 bf16x8 __attribute__((ext_vector_type(8)));
typedef float f32x4 __attribute__((ext_vector_type(4)));

#define NB 16384
#define NA 16
#define ND 256

// XOR swizzle for bf16 LDS tiles [32][256] (row stride 512B): 8-row stripes
// spread over 8 distinct 16B slots; 16-lane column reads -> 2-way (free).
__device__ __forceinline__ int swz(int r, int c) {
    return r * 256 + (c ^ ((r & 7) << 3));
}

// Per-wave 32(M) x 256(K) x 64(N-slice) GEMM. A from swizzled LDS; B row-major
// [N][K] bf16 from global (small L2-resident weight set), depth-2 reg pipeline.
// C/D layout per m89: col = lane&15, row = (lane>>4)*4 + j.
__device__ __forceinline__ void gemm64(const bf16_t* a_lds, const bf16_t* __restrict__ Bg,
                                       f32x4 acc[2][4], int lane, int wc)
{
    const int lr = lane & 15, lhi = lane >> 4;
    const bf16_t* brow = Bg + (wc * 64 + lr) * 256 + lhi * 8;
    bf16x8 bq[2][4];
#pragma unroll
    for (int p = 0; p < 2; ++p)
#pragma unroll
        for (int ni = 0; ni < 4; ++ni)
            bq[p][ni] = *(const bf16x8*)&brow[ni * 4096 + p * 32];
#pragma unroll
    for (int ks = 0; ks < 8; ++ks) {
        const int kc = ks * 32 + lhi * 8;
        bf16x8 af0 = *(const bf16x8*)&a_lds[swz(lr, kc)];
        bf16x8 af1 = *(const bf16x8*)&a_lds[swz(16 + lr, kc)];
#pragma unroll
        for (int ni = 0; ni < 4; ++ni) {
            acc[0][ni] = __builtin_amdgcn_mfma_f32_16x16x32_bf16(af0, bq[ks & 1][ni], acc[0][ni], 0, 0, 0);
            acc[1][ni] = __builtin_amdgcn_mfma_f32_16x16x32_bf16(af1, bq[ks & 1][ni], acc[1][ni], 0, 0, 0);
        }
        if (ks + 2 < 8) {
#pragma unroll
            for (int ni = 0; ni < 4; ++ni)
                bq[ks & 1][ni] = *(const bf16x8*)&brow[ni * 4096 + (ks + 2) * 32];
        }
    }
}

// Stage 32 rows x 256 cols fp32 -> swizzled bf16 LDS tile. Two half-passes of
// 4 f32x4 regs each to bound VGPR use. Row stride in floats.
__device__ __forceinline__ void stage32(const float* __restrict__ base, size_t rstride,
                                        bf16_t* dst, int tid)
{
    const int srr = tid >> 6;          // 0..3
    const int sc4 = (tid & 63) * 4;    // 0..252
#pragma unroll
    for (int h = 0; h < 2; ++h) {
        f32x4 sv[4];
#pragma unroll
        for (int it = 0; it < 4; ++it)
            sv[it] = *(const f32x4*)(base + (size_t)(srr + (h * 4 + it) * 4) * rstride + sc4);
#pragma unroll
        for (int it = 0; it < 4; ++it) {
            int r = srr + (h * 4 + it) * 4;
            bf16x4 s = {(bf16_t)sv[it].x, (bf16_t)sv[it].y, (bf16_t)sv[it].z, (bf16_t)sv[it].w};
            *(bf16x4*)&dst[swz(r, sc4)] = s;
        }
    }
}

// W_agg [D][2D] fp32 -> W1 [D][D] bf16 (k-major), W2 [D][D] bf16.
__global__ void prep_w(const float* __restrict__ W, bf16_t* __restrict__ W1, bf16_t* __restrict__ W2)
{
    int o = blockIdx.x;
    int k = threadIdx.x;
    W1[o * 256 + k] = (bf16_t)W[o * 512 + k];
    W2[o * 256 + k] = (bf16_t)W[o * 512 + 256 + k];
}

// P[a][i][j] fp32 -> Pt[a][j][i] bf16 via LDS 32x32 tile transpose.
__global__ void transpose_P(const float* __restrict__ Pf, const float* __restrict__ Pb,
                            bf16_t* __restrict__ Pft, bf16_t* __restrict__ Pbt)
{
    __shared__ float t[32][33];
    int blk = blockIdx.x;
    int mat = blk >> 10;
    int rest = blk & 1023;
    int a = rest >> 6;
    int tile = rest & 63;
    int i0 = (tile >> 3) * 32;
    int j0 = (tile & 7) * 32;
    const float* src = (mat ? Pb : Pf) + a * 65536;
    bf16_t* dst = (mat ? Pbt : Pft) + a * 65536;
    int r = threadIdx.x >> 5, c = threadIdx.x & 31;
#pragma unroll
    for (int it = 0; it < 4; ++it)
        t[r + 8 * it][c] = src[(i0 + r + 8 * it) * 256 + j0 + c];
    __syncthreads();
#pragma unroll
    for (int it = 0; it < 4; ++it)
        dst[(j0 + r + 8 * it) * 256 + i0 + c] = (bf16_t)t[c][r + 8 * it];
}

// ---- K1: T = img@W1^T + bias (in regs), then per a: agg = T + edge@W2^T -> ws bf16 [a][b][o]
__global__ __launch_bounds__(256, 4)
void k1_agg(const float* __restrict__ img, const float* __restrict__ bias,
            const float* __restrict__ edge,
            const bf16_t* __restrict__ W1, const bf16_t* __restrict__ W2,
            bf16_t* __restrict__ aggws)
{
    __shared__ bf16_t E[2][32 * 256];   // 2 x 16 KB

    const int tid = threadIdx.x;
    const int lane = tid & 63;
    const int wc = tid >> 6;            // 0..3: 64-col slice
    const int lr = lane & 15;
    const int lhi = lane >> 4;
    const int brow0 = blockIdx.x * 32;

    // prologue: img -> E[0]; T = img@W1^T + bias
    stage32(img + (size_t)brow0 * ND, ND, &E[0][0], tid);
    __syncthreads();

    f32x4 T[2][4];
#pragma unroll
    for (int ni = 0; ni < 4; ++ni) {
        float bz = bias[wc * 64 + ni * 16 + lr];
        T[0][ni] = (f32x4){bz, bz, bz, bz};
        T[1][ni] = (f32x4){bz, bz, bz, bz};
    }
    gemm64(&E[0][0], W1, T, lane, wc);
    __syncthreads();                    // E[0] free

    stage32(edge + (size_t)brow0 * (NA * ND), NA * ND, &E[0][0], tid);  // a=0
    __syncthreads();

    for (int a = 0; a < NA; ++a) {
        const int cur = a & 1;
        if (a + 1 < NA)                 // stage a+1 into the other buffer (freed last iter)
            stage32(edge + (size_t)brow0 * (NA * ND) + (size_t)(a + 1) * ND, NA * ND,
                    &E[cur ^ 1][0], tid);
        f32x4 acc[2][4];
#pragma unroll
        for (int mi = 0; mi < 2; ++mi)
#pragma unroll
            for (int ni = 0; ni < 4; ++ni)
                acc[mi][ni] = T[mi][ni];
        gemm64(&E[cur][0], W2, acc, lane, wc);

        bf16_t* op = aggws + ((size_t)a * NB + brow0) * ND;
#pragma unroll
        for (int mi = 0; mi < 2; ++mi)
#pragma unroll
            for (int ni = 0; ni < 4; ++ni)
#pragma unroll
                for (int j = 0; j < 4; ++j) {
                    int r = mi * 16 + lhi * 4 + j;
                    int c = wc * 64 + ni * 16 + lr;
                    op[(size_t)r * ND + c] = (bf16_t)acc[mi][ni][j];
                }
        __syncthreads();
    }
}

// ---- K2: attr[b,a,:] = agg[a,b,:] @ Pf[a] -> fp32 out. One 32-row tile per block.
__global__ __launch_bounds__(256, 4)
void k2_attr(const bf16_t* __restrict__ aggws, const bf16_t* __restrict__ Pf,
             float* __restrict__ out)
{
    __shared__ bf16_t S[32 * 256];      // 16 KB

    const int tid = threadIdx.x;
    const int lane = tid & 63;
    const int wc = tid >> 6;
    const int lr = lane & 15;
    const int lhi = lane >> 4;
    const int a = blockIdx.x >> 9;      // 0..15
    const int brow0 = (blockIdx.x & 511) * 32;

    // stage agg tile (already bf16): 64B per thread
    {
        const bf16_t* src = aggws + ((size_t)a * NB + brow0) * ND;
        const int r = tid >> 3;
        const int cb = (tid & 7) * 32;
#pragma unroll
        for (int q = 0; q < 4; ++q) {
            bf16x8 v = *(const bf16x8*)&src[(size_t)r * ND + cb + q * 8];
            *(bf16x8*)&S[swz(r, cb + q * 8)] = v;
        }
    }
    __syncthreads();

    f32x4 acc[2][4];
#pragma unroll
    for (int mi = 0; mi < 2; ++mi)
#pragma unroll
        for (int ni = 0; ni < 4; ++ni)
            acc[mi][ni] = (f32x4){0.f, 0.f, 0.f, 0.f};
    gemm64(&S[0], Pf + (size_t)a * 65536, acc, lane, wc);

    float* op = out + ((size_t)brow0 * NA + a) * ND;
#pragma unroll
    for (int mi = 0; mi < 2; ++mi)
#pragma unroll
        for (int ni = 0; ni < 4; ++ni)
#pragma unroll
            for (int j = 0; j < 4; ++j) {
                int r = mi * 16 + lhi * 4 + j;
                int c = wc * 64 + ni * 16 + lr;
                op[(size_t)r * (NA * ND) + c] = acc[mi][ni][j];
            }
}

// ---- K3: indiv[b,:] = sum_a relu(attr[b,a,:] @ Pb[a]) * sw[a]. attr read from d_out.
__global__ __launch_bounds__(256, 4)
void k3_indiv(const float* attr, const bf16_t* __restrict__ Pb,
              const float* __restrict__ sw, float* indiv_out)
{
    __shared__ bf16_t S[2][32 * 256];   // 2 x 16 KB

    const int tid = threadIdx.x;
    const int lane = tid & 63;
    const int wc = tid >> 6;
    const int lr = lane & 15;
    const int lhi = lane >> 4;
    const int brow0 = blockIdx.x * 32;

    stage32(attr + (size_t)brow0 * (NA * ND), NA * ND, &S[0][0], tid);  // a=0
    __syncthreads();

    f32x4 indiv[2][4];
#pragma unroll
    for (int mi = 0; mi < 2; ++mi)
#pragma unroll
        for (int ni = 0; ni < 4; ++ni)
            indiv[mi][ni] = (f32x4){0.f, 0.f, 0.f, 0.f};

    for (int a = 0; a < NA; ++a) {
        const int cur = a & 1;
        if (a + 1 < NA)
            stage32(attr + (size_t)brow0 * (NA * ND) + (size_t)(a + 1) * ND, NA * ND,
                    &S[cur ^ 1][0], tid);
        f32x4 acc[2][4];
#pragma unroll
        for (int mi = 0; mi < 2; ++mi)
#pragma unroll
            for (int ni = 0; ni < 4; ++ni)
                acc[mi][ni] = (f32x4){0.f, 0.f, 0.f, 0.f};
        gemm64(&S[cur][0], Pb + (size_t)a * 65536, acc, lane, wc);
        const float swa = sw[a];
#pragma unroll
        for (int mi = 0; mi < 2; ++mi)
#pragma unroll
            for (int ni = 0; ni < 4; ++ni)
#pragma unroll
                for (int j = 0; j < 4; ++j)
                    indiv[mi][ni][j] += fmaxf(acc[mi][ni][j], 0.f) * swa;
        __syncthreads();
    }

#pragma unroll
    for (int mi = 0; mi < 2; ++mi)
#pragma unroll
        for (int ni = 0; ni < 4; ++ni)
#pragma unroll
            for (int j = 0; j < 4; ++j) {
                int r = mi * 16 + lhi * 4 + j;
                int c = wc * 64 + ni * 16 + lr;
                indiv_out[(size_t)(brow0 + r) * ND + c] = indiv[mi][ni][j];
            }
}

extern "C" void kernel_launch(void* const* d_in, const int* in_sizes, int n_in,
                              void* d_out, int out_size, void* d_ws, size_t ws_size,
                              hipStream_t stream)
{
    const float* img  = (const float*)d_in[0];
    const float* edge = (const float*)d_in[1];
    const float* Wagg = (const float*)d_in[2];
    const float* bagg = (const float*)d_in[3];
    const float* Pf   = (const float*)d_in[4];
    const float* Pb   = (const float*)d_in[5];
    const float* sw   = (const float*)d_in[6];
    float* out = (float*)d_out;

    char* ws = (char*)d_ws;
    bf16_t* W1  = (bf16_t*)(ws);                       // 128 KB
    bf16_t* W2  = (bf16_t*)(ws + 131072);              // 128 KB
    bf16_t* Pft = (bf16_t*)(ws + 262144);              // 2 MB
    bf16_t* Pbt = (bf16_t*)(ws + 2359296);             // 2 MB
    bf16_t* agg = (bf16_t*)(ws + 4456448);             // 134.2 MB, [a][b][o] bf16

    prep_w<<<256, 256, 0, stream>>>(Wagg, W1, W2);
    transpose_P<<<2048, 256, 0, stream>>>(Pf, Pb, Pft, Pbt);
    k1_agg<<<NB / 32, 256, 0, stream>>>(img, bagg, edge, W1, W2, agg);
    k2_attr<<<NA * (NB / 32), 256, 0, stream>>>(agg, Pft, out);
    k3_indiv<<<NB / 32, 256, 0, stream>>>(out, Pbt, sw, out + (size_t)NB * NA * ND);
}